// Round 2
// baseline (721.700 us; speedup 1.0000x reference)
//
#include <hip/hip_runtime.h>
#include <hip/hip_bf16.h>
#include <stdint.h>

#define HIDDEN  1024
#define FFN     3584
#define FFN2    7168
#define NE      8
#define NTOK    2048
#define CAP     2048
#define OUT_ELEMS (NTOK * HIDDEN)   /* 2097152 */

/* ---- workspace layout (bytes) ---- */
#define X_OFF   0u                          /* x as bf16: 2048*1024*2 = 4 MiB   */
#define CNT_OFF (4u*1024u*1024u)            /* 8 int counters                   */
#define TOK_OFF (CNT_OFF + 256u)            /* token lists: 8*2048*4 = 64 KiB   */
#define WGT_OFF (TOK_OFF + 65536u)          /* combine weights: 64 KiB          */
#define ACT_OFF (WGT_OFF + 65536u)          /* packed act bf16: 4096*3584*2     */

typedef __attribute__((ext_vector_type(8))) short short8;
typedef __attribute__((ext_vector_type(4))) float floatx4;

static __device__ __forceinline__ uint32_t f2bf(float f) {
  union { float f; uint32_t u; } v; v.f = f;
  return (v.u + 0x7FFFu + ((v.u >> 16) & 1u)) >> 16;   /* RNE */
}
static __device__ __forceinline__ uint32_t pack2(float lo, float hi) {
  return f2bf(lo) | (f2bf(hi) << 16);
}
union S8U { uint4 u; short8 s; };
static __device__ __forceinline__ short8 as_short8(uint4 v) { S8U x; x.u = v; return x.s; }

/* ---- zero output accumulation region + expert counters ---- */
__global__ __launch_bounds__(256) void moe_prep(float4* __restrict__ out4,
                                                int* __restrict__ cnt) {
  uint32_t i = blockIdx.x * 256u + threadIdx.x;   /* 2048 blocks -> 524288 float4 */
  out4[i] = make_float4(0.f, 0.f, 0.f, 0.f);
  if (blockIdx.x == 0 && threadIdx.x < NE) cnt[threadIdx.x] = 0;
}

/* ---- router + x->bf16 convert fused: one wave per token ---- */
__global__ __launch_bounds__(256) void moe_router(
    const float4* __restrict__ x4, const float* __restrict__ gw,
    float* __restrict__ logits, int* __restrict__ cnt,
    int* __restrict__ tok, float* __restrict__ wgt, uint4* __restrict__ xb)
{
  const int w    = threadIdx.x >> 6;
  const int lane = threadIdx.x & 63;
  const int t    = blockIdx.x * 4 + w;
  const float4* xr = x4 + (size_t)t * 256 + lane * 4;   /* 16 floats per lane */
  float4 v0 = xr[0], v1 = xr[1], v2 = xr[2], v3 = xr[3];
  /* bf16 convert: chunks 2*lane, 2*lane+1 (k = lane*16 .. +15) */
  xb[(size_t)t * 128 + lane * 2 + 0] =
      make_uint4(pack2(v0.x, v0.y), pack2(v0.z, v0.w), pack2(v1.x, v1.y), pack2(v1.z, v1.w));
  xb[(size_t)t * 128 + lane * 2 + 1] =
      make_uint4(pack2(v2.x, v2.y), pack2(v2.z, v2.w), pack2(v3.x, v3.y), pack2(v3.z, v3.w));
  float a[NE];
#pragma unroll
  for (int e = 0; e < NE; ++e) {
    const float4* g4 = (const float4*)(gw + e * HIDDEN) + lane * 4;
    float4 g0 = g4[0], g1 = g4[1], g2 = g4[2], g3 = g4[3];
    a[e] = v0.x*g0.x + v0.y*g0.y + v0.z*g0.z + v0.w*g0.w
         + v1.x*g1.x + v1.y*g1.y + v1.z*g1.z + v1.w*g1.w
         + v2.x*g2.x + v2.y*g2.y + v2.z*g2.z + v2.w*g2.w
         + v3.x*g3.x + v3.y*g3.y + v3.z*g3.z + v3.w*g3.w;
  }
#pragma unroll
  for (int off = 32; off > 0; off >>= 1) {
#pragma unroll
    for (int e = 0; e < NE; ++e) a[e] += __shfl_xor(a[e], off);
  }
  if (lane == 0) {
#pragma unroll
    for (int e = 0; e < NE; ++e) logits[t * NE + e] = a[e];
    int i0 = 0; float v0s = a[0];
#pragma unroll
    for (int e = 1; e < NE; ++e) if (a[e] > v0s) { v0s = a[e]; i0 = e; }
    int i1 = (i0 == 0) ? 1 : 0; float v1s = a[i1];
#pragma unroll
    for (int e = 0; e < NE; ++e) if (e != i0 && a[e] > v1s) { v1s = a[e]; i1 = e; }
    float w0 = 1.f / (1.f + __expf(v1s - v0s));
    float w1 = 1.f - w0;
    int p0 = atomicAdd(&cnt[i0], 1); tok[i0 * CAP + p0] = t; wgt[i0 * CAP + p0] = w0;
    int p1 = atomicAdd(&cnt[i1], 1); tok[i1 * CAP + p1] = t; wgt[i1 * CAP + p1] = w1;
  }
}

/* ==== grouped GEMM 1: act = silu(x@Wg)*(x@Wu); BM=512 BNf=32(64 logical) BK=32 ====
 * Read-once streaming: 512 threads / 8 waves; wave w = rows [w*64, w*64+64).
 * B (fp32 weights) register-prefetched 1 kt ahead, packed bf16 into padded LDS. */
__global__ __launch_bounds__(512) void moe_gateup(
    const uint4* __restrict__ xb, const float* __restrict__ wgu,
    const int* __restrict__ cnt, const int* __restrict__ tok,
    unsigned short* __restrict__ act)
{
  const int e  = blockIdx.z;
  const int m0 = blockIdx.y * 512;
  const int f0 = blockIdx.x * 32;
  const int cn = cnt[e];
  if (m0 >= cn) return;
  int basev = 0;
#pragma unroll
  for (int i = 0; i < NE; ++i) { int ci = cnt[i]; if (i < e) basev += ci; }

  __shared__ uint4    As[512 * 5];   /* row*5 + c8 (c8 in [0,4), +1 pad chunk) */
  __shared__ uint32_t Bs[16 * 66];   /* k-pair words, row pad 66 for banks     */

  const int tid  = threadIdx.x;
  const int lane = tid & 63;
  const int w    = tid >> 6;
  const int q    = lane >> 4;
  const int c    = lane & 15;

  /* A staging precompute (gathered token rows; constant across kt) */
  int aoff[4], alds[4];
#pragma unroll
  for (int it = 0; it < 4; ++it) {
    int cid = it * 512 + tid;
    int row = cid >> 2, c8 = cid & 3;
    int mrow = m0 + row; if (mrow >= cn) mrow = cn - 1;
    int tk = tok[e * CAP + mrow];
    aoff[it] = tk * 128 + c8;       /* + kt*4 per iteration */
    alds[it] = row * 5 + c8;
  }

  floatx4 acc[4][4];
#pragma unroll
  for (int i = 0; i < 4; ++i)
#pragma unroll
    for (int j = 0; j < 4; ++j) acc[i][j] = (floatx4){0.f, 0.f, 0.f, 0.f};

  const float* wB = wgu + (size_t)e * HIDDEN * FFN2;
  /* B prefetch coords: thread owns k-pair kp, 2 logical cols n2,n2+1 */
  const int kp = tid >> 5;          /* [0,16) */
  const int n2 = (tid & 31) * 2;    /* [0,64) */
  const int bcol = (n2 < 32) ? (f0 + n2) : (FFN + f0 + (n2 - 32));
  const float* bsrc = wB + (size_t)(2 * kp) * FFN2 + bcol;
  float2 r0 = *(const float2*)(bsrc);
  float2 r1 = *(const float2*)(bsrc + FFN2);

  for (int kt = 0; kt < 32; ++kt) {
    __syncthreads();
    *(uint2*)&Bs[kp * 66 + n2] = make_uint2(pack2(r0.x, r1.x), pack2(r0.y, r1.y));
#pragma unroll
    for (int it = 0; it < 4; ++it) As[alds[it]] = xb[aoff[it] + kt * 4];
    __syncthreads();
    /* prefetch next kt while computing this one */
    int kn = (kt + 1 < 32) ? (kt + 1) : 31;
    const float* nb = bsrc + (size_t)kn * 32 * FFN2;
    r0 = *(const float2*)(nb);
    r1 = *(const float2*)(nb + FFN2);

    short8 af[4];
#pragma unroll
    for (int i = 0; i < 4; ++i) af[i] = as_short8(As[(w * 64 + i * 16 + c) * 5 + q]);
    short8 bfr[4];
#pragma unroll
    for (int j = 0; j < 4; ++j) {
      int b0 = (q * 4) * 66 + j * 16 + c;
      bfr[j] = as_short8(make_uint4(Bs[b0], Bs[b0 + 66], Bs[b0 + 132], Bs[b0 + 198]));
    }
#pragma unroll
    for (int i = 0; i < 4; ++i)
#pragma unroll
      for (int j = 0; j < 4; ++j)
        acc[i][j] = __builtin_amdgcn_mfma_f32_16x16x32_bf16(af[i], bfr[j], acc[i][j], 0, 0, 0);
  }

  /* epilogue: silu(gate)*up -> packed act rows (gate frag j pairs with up frag j+2) */
#pragma unroll
  for (int i = 0; i < 4; ++i) {
#pragma unroll
    for (int r = 0; r < 4; ++r) {
      int m = m0 + w * 64 + i * 16 + q * 4 + r;
      if (m < cn) {
#pragma unroll
        for (int j = 0; j < 2; ++j) {
          float g = acc[i][j][r];
          float u = acc[i][j + 2][r];
          float a = (g / (1.f + __expf(-g))) * u;
          act[(size_t)(basev + m) * FFN + (f0 + j * 16 + c)] = (unsigned short)f2bf(a);
        }
      }
    }
  }
}

/* ==== grouped GEMM 2: out[t] += w*(act@Wd); BM=512 BN=64 BK=32, K split by 4 ==== */
__global__ __launch_bounds__(512) void moe_down(
    const uint4* __restrict__ actc, const float* __restrict__ wd,
    const int* __restrict__ cnt, const int* __restrict__ tok,
    const float* __restrict__ wgt, float* __restrict__ out)
{
  const int bz = blockIdx.z;
  const int e  = bz >> 2;
  const int sl = bz & 3;            /* K slice: [sl*896, sl*896+896) */
  const int m0 = blockIdx.y * 512;
  const int n0 = blockIdx.x * 64;
  const int cn = cnt[e];
  if (m0 >= cn) return;
  int basev = 0;
#pragma unroll
  for (int i = 0; i < NE; ++i) { int ci = cnt[i]; if (i < e) basev += ci; }

  __shared__ uint4    As[512 * 5];
  __shared__ uint32_t Bs[16 * 66];

  const int tid  = threadIdx.x;
  const int lane = tid & 63;
  const int w    = tid >> 6;
  const int q    = lane >> 4;
  const int c    = lane & 15;

  int aoff[4], alds[4];
#pragma unroll
  for (int it = 0; it < 4; ++it) {
    int cid = it * 512 + tid;
    int row = cid >> 2, c8 = cid & 3;
    int mrow = m0 + row; if (mrow >= cn) mrow = cn - 1;
    aoff[it] = (basev + mrow) * 448 + sl * 112 + c8;
    alds[it] = row * 5 + c8;
  }

  floatx4 acc[4][4];
#pragma unroll
  for (int i = 0; i < 4; ++i)
#pragma unroll
    for (int j = 0; j < 4; ++j) acc[i][j] = (floatx4){0.f, 0.f, 0.f, 0.f};

  const float* wB = wd + (size_t)e * FFN * HIDDEN;
  const int kp = tid >> 5;
  const int n2 = (tid & 31) * 2;
  const int col = n0 + n2;
  const float* bsrc = wB + (size_t)(sl * 896 + 2 * kp) * HIDDEN + col;
  float2 r0 = *(const float2*)(bsrc);
  float2 r1 = *(const float2*)(bsrc + HIDDEN);

  for (int kt = 0; kt < 28; ++kt) {
    __syncthreads();
    *(uint2*)&Bs[kp * 66 + n2] = make_uint2(pack2(r0.x, r1.x), pack2(r0.y, r1.y));
#pragma unroll
    for (int it = 0; it < 4; ++it) As[alds[it]] = actc[aoff[it] + kt * 4];
    __syncthreads();
    int kn = (kt + 1 < 28) ? (kt + 1) : 27;
    const float* nb = bsrc + (size_t)kn * 32 * HIDDEN;
    r0 = *(const float2*)(nb);
    r1 = *(const float2*)(nb + HIDDEN);

    short8 af[4];
#pragma unroll
    for (int i = 0; i < 4; ++i) af[i] = as_short8(As[(w * 64 + i * 16 + c) * 5 + q]);
    short8 bfr[4];
#pragma unroll
    for (int j = 0; j < 4; ++j) {
      int b0 = (q * 4) * 66 + j * 16 + c;
      bfr[j] = as_short8(make_uint4(Bs[b0], Bs[b0 + 66], Bs[b0 + 132], Bs[b0 + 198]));
    }
#pragma unroll
    for (int i = 0; i < 4; ++i)
#pragma unroll
      for (int j = 0; j < 4; ++j)
        acc[i][j] = __builtin_amdgcn_mfma_f32_16x16x32_bf16(af[i], bfr[j], acc[i][j], 0, 0, 0);
  }

  /* epilogue: scale by combine weight, scatter-add into output */
#pragma unroll
  for (int i = 0; i < 4; ++i) {
#pragma unroll
    for (int r = 0; r < 4; ++r) {
      int m = m0 + w * 64 + i * 16 + q * 4 + r;
      if (m < cn) {
        int   t  = tok[e * CAP + m];
        float wg = wgt[e * CAP + m];
        float* orow = out + (size_t)t * HIDDEN + n0 + c;
#pragma unroll
        for (int j = 0; j < 4; ++j)
          atomicAdd(orow + j * 16, acc[i][j][r] * wg);
      }
    }
  }
}

extern "C" void kernel_launch(void* const* d_in, const int* in_sizes, int n_in,
                              void* d_out, int out_size, void* d_ws, size_t ws_size,
                              hipStream_t stream)
{
  (void)in_sizes; (void)n_in; (void)out_size; (void)ws_size;
  const float* x   = (const float*)d_in[0];
  const float* gw  = (const float*)d_in[1];
  const float* wgu = (const float*)d_in[2];
  const float* wd  = (const float*)d_in[3];
  float* out = (float*)d_out;
  char*  ws  = (char*)d_ws;

  uint4*          xb  = (uint4*)(ws + X_OFF);
  int*            cnt = (int*)(ws + CNT_OFF);
  int*            tok = (int*)(ws + TOK_OFF);
  float*          wgt = (float*)(ws + WGT_OFF);
  unsigned short* act = (unsigned short*)(ws + ACT_OFF);

  moe_prep<<<OUT_ELEMS / (256 * 4), 256, 0, stream>>>((float4*)out, cnt);
  moe_router<<<NTOK / 4, 256, 0, stream>>>((const float4*)x, gw, out + OUT_ELEMS,
                                           cnt, tok, wgt, xb);
  moe_gateup<<<dim3(FFN / 32, 4, NE), 512, 0, stream>>>(xb, wgu, cnt, tok, act);
  moe_down<<<dim3(HIDDEN / 64, 4, NE * 4), 512, 0, stream>>>((const uint4*)act, wd,
                                                             cnt, tok, wgt, out);
}

// Round 3
// 652.212 us; speedup vs baseline: 1.1065x; 1.1065x over previous
//
#include <hip/hip_runtime.h>
#include <hip/hip_bf16.h>
#include <stdint.h>

#define HIDDEN  1024
#define FFN     3584
#define FFN2    7168
#define NE      8
#define NTOK    2048
#define CAP     2048
#define OUT_ELEMS (NTOK * HIDDEN)   /* 2097152 */

/* ---- workspace layout (bytes) ---- */
#define X_OFF   0u                          /* x as bf16: 2048*1024*2 = 4 MiB   */
#define CNT_OFF (4u*1024u*1024u)            /* 8 int counters                   */
#define TOK_OFF (CNT_OFF + 256u)            /* token lists: 8*2048*4 = 64 KiB   */
#define WGT_OFF (TOK_OFF + 65536u)          /* combine weights: 64 KiB          */
#define ACT_OFF (WGT_OFF + 65536u)          /* packed act bf16: 4096*3584*2     */

typedef __attribute__((ext_vector_type(8))) short short8;
typedef __attribute__((ext_vector_type(4))) float floatx4;

static __device__ __forceinline__ uint32_t f2bf(float f) {
  union { float f; uint32_t u; } v; v.f = f;
  return (v.u + 0x7FFFu + ((v.u >> 16) & 1u)) >> 16;   /* RNE */
}
static __device__ __forceinline__ uint32_t pack2(float lo, float hi) {
  return f2bf(lo) | (f2bf(hi) << 16);
}
union S8U { uint4 u; short8 s; };
static __device__ __forceinline__ short8 as_short8(uint4 v) { S8U x; x.u = v; return x.s; }

/* As LDS index: 2 rows per 32-word line, slot' = ((row&1)<<2 | c8) ^ ((row>>1)&7).
 * Row-line base mod 32 banks = 0; verified-free b128 pattern (R1, 0 conflicts). */
static __device__ __forceinline__ int a_idx(int row, int c8) {
  return (row >> 1) * 8 + ((((row & 1) << 2) | c8) ^ ((row >> 1) & 7));
}

/* ---- zero output accumulation region + expert counters ---- */
__global__ __launch_bounds__(256) void moe_prep(float4* __restrict__ out4,
                                                int* __restrict__ cnt) {
  uint32_t i = blockIdx.x * 256u + threadIdx.x;
  out4[i] = make_float4(0.f, 0.f, 0.f, 0.f);
  if (blockIdx.x == 0 && threadIdx.x < NE) cnt[threadIdx.x] = 0;
}

/* ---- router + x->bf16 convert fused: one wave per token ---- */
__global__ __launch_bounds__(256) void moe_router(
    const float4* __restrict__ x4, const float* __restrict__ gw,
    float* __restrict__ logits, int* __restrict__ cnt,
    int* __restrict__ tok, float* __restrict__ wgt, uint4* __restrict__ xb)
{
  const int w    = threadIdx.x >> 6;
  const int lane = threadIdx.x & 63;
  const int t    = blockIdx.x * 4 + w;
  const float4* xr = x4 + (size_t)t * 256 + lane * 4;
  float4 v0 = xr[0], v1 = xr[1], v2 = xr[2], v3 = xr[3];
  xb[(size_t)t * 128 + lane * 2 + 0] =
      make_uint4(pack2(v0.x, v0.y), pack2(v0.z, v0.w), pack2(v1.x, v1.y), pack2(v1.z, v1.w));
  xb[(size_t)t * 128 + lane * 2 + 1] =
      make_uint4(pack2(v2.x, v2.y), pack2(v2.z, v2.w), pack2(v3.x, v3.y), pack2(v3.z, v3.w));
  float a[NE];
#pragma unroll
  for (int e = 0; e < NE; ++e) {
    const float4* g4 = (const float4*)(gw + e * HIDDEN) + lane * 4;
    float4 g0 = g4[0], g1 = g4[1], g2 = g4[2], g3 = g4[3];
    a[e] = v0.x*g0.x + v0.y*g0.y + v0.z*g0.z + v0.w*g0.w
         + v1.x*g1.x + v1.y*g1.y + v1.z*g1.z + v1.w*g1.w
         + v2.x*g2.x + v2.y*g2.y + v2.z*g2.z + v2.w*g2.w
         + v3.x*g3.x + v3.y*g3.y + v3.z*g3.z + v3.w*g3.w;
  }
#pragma unroll
  for (int off = 32; off > 0; off >>= 1) {
#pragma unroll
    for (int e = 0; e < NE; ++e) a[e] += __shfl_xor(a[e], off);
  }
  if (lane == 0) {
#pragma unroll
    for (int e = 0; e < NE; ++e) logits[t * NE + e] = a[e];
    int i0 = 0; float v0s = a[0];
#pragma unroll
    for (int e = 1; e < NE; ++e) if (a[e] > v0s) { v0s = a[e]; i0 = e; }
    int i1 = (i0 == 0) ? 1 : 0; float v1s = a[i1];
#pragma unroll
    for (int e = 0; e < NE; ++e) if (e != i0 && a[e] > v1s) { v1s = a[e]; i1 = e; }
    float w0 = 1.f / (1.f + __expf(v1s - v0s));
    float w1 = 1.f - w0;
    int p0 = atomicAdd(&cnt[i0], 1); tok[i0 * CAP + p0] = t; wgt[i0 * CAP + p0] = w0;
    int p1 = atomicAdd(&cnt[i1], 1); tok[i1 * CAP + p1] = t; wgt[i1 * CAP + p1] = w1;
  }
}

/* ==== grouped GEMM 1: act = silu(x@Wg)*(x@Wu)
 * BM=256, BN=128 logical (64 f-cols x {gate,up}), BK=32, 512 thr / 8 waves (4m x 2n).
 * A and B register-prefetched one kt ahead; barriers fence only reg->LDS writes. ==== */
__global__ __launch_bounds__(512) void moe_gateup(
    const uint4* __restrict__ xb, const float* __restrict__ wgu,
    const int* __restrict__ cnt, const int* __restrict__ tok,
    unsigned short* __restrict__ act)
{
  const int e  = blockIdx.z;
  const int m0 = blockIdx.y * 256;
  const int f0 = blockIdx.x * 64;
  const int cn = cnt[e];
  if (m0 >= cn) return;
  int basev = 0;
#pragma unroll
  for (int i = 0; i < NE; ++i) { int ci = cnt[i]; if (i < e) basev += ci; }

  __shared__ uint4    As[1024];   /* 256 rows x 4 chunks, a_idx layout, 16 KB */
  __shared__ uint32_t Bs[2048];   /* 16 kp x 128 n, XOR-swizzled, 8 KB       */

  const int tid  = threadIdx.x;
  const int lane = tid & 63;
  const int w    = tid >> 6;
  const int wm   = w >> 1, wn = w & 1;
  const int q    = lane >> 4;
  const int c    = lane & 15;

  /* A staging: 1024 chunks, 2 per thread (constant coords across kt) */
  int aoff0, aoff1, alds0, alds1;
  {
    int cid = tid;            int row = cid >> 2, c8 = cid & 3;
    int mrow = m0 + row; if (mrow >= cn) mrow = cn - 1;
    aoff0 = tok[e * CAP + mrow] * 128 + c8;  alds0 = a_idx(row, c8);
    cid = 512 + tid;          row = cid >> 2; c8 = cid & 3;
    mrow = m0 + row; if (mrow >= cn) mrow = cn - 1;
    aoff1 = tok[e * CAP + mrow] * 128 + c8;  alds1 = a_idx(row, c8);
  }

  /* B staging: thread owns k-pair kp, 4 logical cols n4..n4+3 */
  const int kp = tid >> 5;
  const int n4 = (tid & 31) * 4;
  const int bcol = f0 + ((n4 >> 6) & 1) * 32 + ((n4 >> 4) & 1) * 16 + (n4 & 15)
                 + ((n4 >> 5) & 1) * FFN;
  const float* bsrc = wgu + (size_t)e * HIDDEN * FFN2 + (size_t)(2 * kp) * FFN2 + bcol;
  const int bw = kp * 128 + (n4 ^ (((kp >> 2) & 1) << 4));

  floatx4 acc[4][4];
#pragma unroll
  for (int i = 0; i < 4; ++i)
#pragma unroll
    for (int j = 0; j < 4; ++j) acc[i][j] = (floatx4){0.f, 0.f, 0.f, 0.f};

  /* prefetch kt=0 */
  uint4  pa0 = xb[aoff0], pa1 = xb[aoff1];
  float4 pb0 = *(const float4*)bsrc;
  float4 pb1 = *(const float4*)(bsrc + FFN2);

  for (int kt = 0; kt < 32; ++kt) {
    __syncthreads();
    As[alds0] = pa0;
    As[alds1] = pa1;
    *(uint4*)&Bs[bw] = make_uint4(pack2(pb0.x, pb1.x), pack2(pb0.y, pb1.y),
                                  pack2(pb0.z, pb1.z), pack2(pb0.w, pb1.w));
    __syncthreads();
    int kn = (kt + 1 < 32) ? (kt + 1) : 31;
    pa0 = xb[aoff0 + kn * 4];
    pa1 = xb[aoff1 + kn * 4];
    const float* nb = bsrc + (size_t)kn * 32 * FFN2;
    pb0 = *(const float4*)nb;
    pb1 = *(const float4*)(nb + FFN2);

    short8 af[4];
#pragma unroll
    for (int i = 0; i < 4; ++i) {
      int row = wm * 64 + i * 16 + c;
      af[i] = as_short8(As[a_idx(row, q)]);
    }
    short8 bfr[4];
#pragma unroll
    for (int j = 0; j < 4; ++j) {
      int nn = (wn * 64 + j * 16 + c) ^ ((q & 1) << 4);
      int b0 = (q * 4) * 128 + nn;
      bfr[j] = as_short8(make_uint4(Bs[b0], Bs[b0 + 128], Bs[b0 + 256], Bs[b0 + 384]));
    }
#pragma unroll
    for (int i = 0; i < 4; ++i)
#pragma unroll
      for (int j = 0; j < 4; ++j)
        acc[i][j] = __builtin_amdgcn_mfma_f32_16x16x32_bf16(af[i], bfr[j], acc[i][j], 0, 0, 0);
  }

  /* epilogue: silu(gate j)*up(j+2) -> packed act */
#pragma unroll
  for (int i = 0; i < 4; ++i) {
#pragma unroll
    for (int r = 0; r < 4; ++r) {
      int m = m0 + wm * 64 + i * 16 + q * 4 + r;
      if (m < cn) {
#pragma unroll
        for (int j = 0; j < 2; ++j) {
          float g = acc[i][j][r];
          float u = acc[i][j + 2][r];
          float a = (g / (1.f + __expf(-g))) * u;
          act[(size_t)(basev + m) * FFN + (f0 + wn * 32 + j * 16 + c)] = (unsigned short)f2bf(a);
        }
      }
    }
  }
}

/* ==== grouped GEMM 2: out[t] += w*(act@Wd)
 * BM=256, BN=128, BK=32, K split by 4 (896 each), same pipeline/layouts. ==== */
__global__ __launch_bounds__(512) void moe_down(
    const uint4* __restrict__ actc, const float* __restrict__ wd,
    const int* __restrict__ cnt, const int* __restrict__ tok,
    const float* __restrict__ wgt, float* __restrict__ out)
{
  const int bz = blockIdx.z;
  const int e  = bz >> 2;
  const int sl = bz & 3;
  const int m0 = blockIdx.y * 256;
  const int n0 = blockIdx.x * 128;
  const int cn = cnt[e];
  if (m0 >= cn) return;
  int basev = 0;
#pragma unroll
  for (int i = 0; i < NE; ++i) { int ci = cnt[i]; if (i < e) basev += ci; }

  __shared__ uint4    As[1024];
  __shared__ uint32_t Bs[2048];

  const int tid  = threadIdx.x;
  const int lane = tid & 63;
  const int w    = tid >> 6;
  const int wm   = w >> 1, wn = w & 1;
  const int q    = lane >> 4;
  const int c    = lane & 15;

  int aoff0, aoff1, alds0, alds1;
  {
    int cid = tid;            int row = cid >> 2, c8 = cid & 3;
    int mrow = m0 + row; if (mrow >= cn) mrow = cn - 1;
    aoff0 = (basev + mrow) * 448 + sl * 112 + c8;  alds0 = a_idx(row, c8);
    cid = 512 + tid;          row = cid >> 2; c8 = cid & 3;
    mrow = m0 + row; if (mrow >= cn) mrow = cn - 1;
    aoff1 = (basev + mrow) * 448 + sl * 112 + c8;  alds1 = a_idx(row, c8);
  }

  const int kp = tid >> 5;
  const int n4 = (tid & 31) * 4;
  const float* bsrc = wd + (size_t)e * FFN * HIDDEN
                    + (size_t)(sl * 896 + 2 * kp) * HIDDEN + n0 + n4;
  const int bw = kp * 128 + (n4 ^ (((kp >> 2) & 1) << 4));

  floatx4 acc[4][4];
#pragma unroll
  for (int i = 0; i < 4; ++i)
#pragma unroll
    for (int j = 0; j < 4; ++j) acc[i][j] = (floatx4){0.f, 0.f, 0.f, 0.f};

  uint4  pa0 = actc[aoff0], pa1 = actc[aoff1];
  float4 pb0 = *(const float4*)bsrc;
  float4 pb1 = *(const float4*)(bsrc + HIDDEN);

  for (int kt = 0; kt < 28; ++kt) {
    __syncthreads();
    As[alds0] = pa0;
    As[alds1] = pa1;
    *(uint4*)&Bs[bw] = make_uint4(pack2(pb0.x, pb1.x), pack2(pb0.y, pb1.y),
                                  pack2(pb0.z, pb1.z), pack2(pb0.w, pb1.w));
    __syncthreads();
    int kn = (kt + 1 < 28) ? (kt + 1) : 27;
    pa0 = actc[aoff0 + kn * 4];
    pa1 = actc[aoff1 + kn * 4];
    const float* nb = bsrc + (size_t)kn * 32 * HIDDEN;
    pb0 = *(const float4*)nb;
    pb1 = *(const float4*)(nb + HIDDEN);

    short8 af[4];
#pragma unroll
    for (int i = 0; i < 4; ++i) {
      int row = wm * 64 + i * 16 + c;
      af[i] = as_short8(As[a_idx(row, q)]);
    }
    short8 bfr[4];
#pragma unroll
    for (int j = 0; j < 4; ++j) {
      int nn = (wn * 64 + j * 16 + c) ^ ((q & 1) << 4);
      int b0 = (q * 4) * 128 + nn;
      bfr[j] = as_short8(make_uint4(Bs[b0], Bs[b0 + 128], Bs[b0 + 256], Bs[b0 + 384]));
    }
#pragma unroll
    for (int i = 0; i < 4; ++i)
#pragma unroll
      for (int j = 0; j < 4; ++j)
        acc[i][j] = __builtin_amdgcn_mfma_f32_16x16x32_bf16(af[i], bfr[j], acc[i][j], 0, 0, 0);
  }

#pragma unroll
  for (int i = 0; i < 4; ++i) {
#pragma unroll
    for (int r = 0; r < 4; ++r) {
      int m = m0 + wm * 64 + i * 16 + q * 4 + r;
      if (m < cn) {
        int   t  = tok[e * CAP + m];
        float wg = wgt[e * CAP + m];
        float* orow = out + (size_t)t * HIDDEN + n0 + wn * 64 + c;
#pragma unroll
        for (int j = 0; j < 4; ++j)
          atomicAdd(orow + j * 16, acc[i][j][r] * wg);
      }
    }
  }
}

extern "C" void kernel_launch(void* const* d_in, const int* in_sizes, int n_in,
                              void* d_out, int out_size, void* d_ws, size_t ws_size,
                              hipStream_t stream)
{
  (void)in_sizes; (void)n_in; (void)out_size; (void)ws_size;
  const float* x   = (const float*)d_in[0];
  const float* gw  = (const float*)d_in[1];
  const float* wgu = (const float*)d_in[2];
  const float* wd  = (const float*)d_in[3];
  float* out = (float*)d_out;
  char*  ws  = (char*)d_ws;

  uint4*          xb  = (uint4*)(ws + X_OFF);
  int*            cnt = (int*)(ws + CNT_OFF);
  int*            tok = (int*)(ws + TOK_OFF);
  float*          wgt = (float*)(ws + WGT_OFF);
  unsigned short* act = (unsigned short*)(ws + ACT_OFF);

  moe_prep<<<OUT_ELEMS / (256 * 4), 256, 0, stream>>>((float4*)out, cnt);
  moe_router<<<NTOK / 4, 256, 0, stream>>>((const float4*)x, gw, out + OUT_ELEMS,
                                           cnt, tok, wgt, xb);
  moe_gateup<<<dim3(FFN / 64, 8, NE), 512, 0, stream>>>(xb, wgu, cnt, tok, act);
  moe_down<<<dim3(HIDDEN / 128, 8, NE * 4), 512, 0, stream>>>((const uint4*)act, wd,
                                                              cnt, tok, wgt, out);
}